// Round 5
// baseline (671.117 us; speedup 1.0000x reference)
//
#include <hip/hip_runtime.h>
#include <math.h>

#define N_NODES  100000
#define N_FEAT   128
#define N_HID    64
#define N_CLASS  10
#define N_GRAPHS 1000
#define N_EDGES  1600000
#define SCAN_NB  98        // ceil(100000/1024)
#define NPASS    6
#define PRANGE   16667     // ceil(100000/6)
#define NTILES   1563      // ceil(100000/64)

// ---------------- zero int array ----------------
__global__ __launch_bounds__(256) void zero_kernel(int* __restrict__ p, int n)
{
    int stride = gridDim.x * blockDim.x;
    for (int i = blockIdx.x * blockDim.x + threadIdx.x; i < n; i += stride)
        p[i] = 0;
}

// ---- degree histogram over dst; atomic return value IS the edge's rank ----
__global__ __launch_bounds__(256) void hist_kernel(
    const int* __restrict__ ei, int* __restrict__ deg, int* __restrict__ rank)
{
    int stride = gridDim.x * blockDim.x;
    for (int e = blockIdx.x * blockDim.x + threadIdx.x; e < N_EDGES; e += stride)
        rank[e] = atomicAdd(&deg[ei[N_EDGES + e]], 1);
}

// ---------------- scan stage 1: per-block (1024 elems) exclusive scan ----------
__global__ __launch_bounds__(256) void scan1_kernel(
    const int* __restrict__ deg, int* __restrict__ pre, int* __restrict__ bsum)
{
    __shared__ int tsum[256];
    const int base = blockIdx.x * 1024 + threadIdx.x * 4;
    int v[4];
#pragma unroll
    for (int j = 0; j < 4; ++j)
        v[j] = (base + j < N_NODES) ? deg[base + j] : 0;
    int run = 0;
#pragma unroll
    for (int j = 0; j < 4; ++j) { int t = v[j]; v[j] = run; run += t; }
    tsum[threadIdx.x] = run;
    __syncthreads();
    for (int off = 1; off < 256; off <<= 1) {
        int t = (threadIdx.x >= off) ? tsum[threadIdx.x - off] : 0;
        __syncthreads();
        tsum[threadIdx.x] += t;
        __syncthreads();
    }
    const int excl = (threadIdx.x > 0) ? tsum[threadIdx.x - 1] : 0;
#pragma unroll
    for (int j = 0; j < 4; ++j)
        if (base + j < N_NODES) pre[base + j] = v[j] + excl;
    if (threadIdx.x == 255) bsum[blockIdx.x] = tsum[255];
}

// ---------------- scan stage 2: serial scan of 98 block sums ----------------
__global__ void scan2_kernel(int* __restrict__ bsum)
{
    if (threadIdx.x == 0 && blockIdx.x == 0) {
        int run = 0;
        for (int i = 0; i < SCAN_NB; ++i) { int t = bsum[i]; bsum[i] = run; run += t; }
    }
}

// ---------------- scan stage 3: add block offset -> row ptr ----------------
__global__ __launch_bounds__(256) void scan3_kernel(
    const int* __restrict__ pre, const int* __restrict__ bsum,
    int* __restrict__ row)
{
    int stride = gridDim.x * blockDim.x;
    for (int i = blockIdx.x * blockDim.x + threadIdx.x; i < N_NODES; i += stride)
        row[i] = pre[i] + bsum[i >> 10];
}

// ---- CSR fill: no atomics (pos = row[d]+rank[e]); 6 dst-range passes so the
// ---- active csr/row window (~1.1 MB / 67 KB) stays L2-resident ----
__global__ __launch_bounds__(256) void fill_kernel(
    const int* __restrict__ ei, const int* __restrict__ rank,
    const int* __restrict__ row, int* __restrict__ csr)
{
    const int stride = gridDim.x * blockDim.x;
    const int tid0 = blockIdx.x * blockDim.x + threadIdx.x;
    for (int pass = 0; pass < NPASS; ++pass) {
        const int lo = pass * PRANGE;
        const int hi = lo + PRANGE;
        for (int e = tid0; e < N_EDGES; e += stride) {
            const int d = ei[N_EDGES + e];
            if (d >= lo && d < hi)
                csr[row[d] + rank[e]] = ei[e];
        }
    }
}

// ---- gather: agg[i] = h[i] + sum_{e in row[i]} h[csr[e]] ----
// one wave per node; uniform trip count so every __shfl source lane is active
// (ds_bpermute from an inactive lane is undefined — round-3 bug).
__global__ __launch_bounds__(256) void gather_kernel(
    const float* __restrict__ h, float* __restrict__ agg,
    const int* __restrict__ csr, const int* __restrict__ row,
    const int* __restrict__ deg)
{
    const int lane = threadIdx.x & 63;
    const int grp  = lane >> 4;       // 0..3
    const int sub  = lane & 15;       // 0..15
    const int nw = gridDim.x * 4;
    for (int node = blockIdx.x * 4 + (threadIdx.x >> 6); node < N_NODES; node += nw) {
        const int un = __builtin_amdgcn_readfirstlane(node);
        const int lo = __builtin_amdgcn_readfirstlane(row[un]);
        const int n  = __builtin_amdgcn_readfirstlane(deg[un]);
        int eidx = 0;
        if (lane < n) eidx = csr[lo + lane];    // whole bucket, one load
        float ax = 0.f, ay = 0.f, az = 0.f, aw = 0.f;
        if (grp == 0) {
            const float4 a = *(const float4*)(h + (size_t)un * N_HID + (sub << 2));
            ax += a.x; ay += a.y; az += a.z; aw += a.w;
        }
        for (int eb = 0; eb < n; eb += 8) {     // UNIFORM trip count
            const int j0 = eb + grp;
            const int j1 = j0 + 4;
            const int s0 = __shfl(eidx, j0, 64);
            const int s1 = __shfl(eidx, j1, 64);
            if (j0 < n) {
                const float4 a = *(const float4*)(h + (size_t)s0 * N_HID + (sub << 2));
                ax += a.x; ay += a.y; az += a.z; aw += a.w;
            }
            if (j1 < n) {
                const float4 a = *(const float4*)(h + (size_t)s1 * N_HID + (sub << 2));
                ax += a.x; ay += a.y; az += a.z; aw += a.w;
            }
        }
        ax += __shfl_xor(ax, 16, 64); ay += __shfl_xor(ay, 16, 64);
        az += __shfl_xor(az, 16, 64); aw += __shfl_xor(aw, 16, 64);
        ax += __shfl_xor(ax, 32, 64); ay += __shfl_xor(ay, 32, 64);
        az += __shfl_xor(az, 32, 64); aw += __shfl_xor(aw, 32, 64);
        if (grp == 0) {
            float4 r = make_float4(ax, ay, az, aw);
            *(float4*)(agg + (size_t)un * N_HID + (sub << 2)) = r;
        }
    }
}

// ---- pre v2: LDS-tiled GEMM. 64 nodes x 64 cols per block; W staged in two
// 64-row halves (LDS 50 KB -> 3 blocks/CU). 16x16 threads, 4x4 micro-tile,
// ds_read_b128 operands. Nodes strided m=ty+16i => a-read banks 2-way (free).
__global__ __launch_bounds__(256) void pre_kernel(
    const float* __restrict__ x, const float* __restrict__ W,
    const float* __restrict__ b, float* __restrict__ h)
{
    __shared__ float xs[64][132];   // x tile [m][k], pad 4 keeps b128 alignment
    __shared__ float ws[64][68];    // W half  [kk][c]
    const int tid = threadIdx.x;
    const int tx = tid & 15, ty = tid >> 4;
    const int n0 = blockIdx.x * 64;

    // x tile: 2048 float4, 8 per thread, rows contiguous in global (coalesced)
#pragma unroll
    for (int t = 0; t < 8; ++t) {
        const int idx = t * 256 + tid;
        const int m = idx >> 5, kv = idx & 31;
        float4 v = make_float4(0.f, 0.f, 0.f, 0.f);
        if (n0 + m < N_NODES)
            v = *(const float4*)(x + (size_t)(n0 + m) * N_FEAT + kv * 4);
        *(float4*)&xs[m][kv * 4] = v;
    }

    float acc[4][4];
#pragma unroll
    for (int i = 0; i < 4; ++i)
#pragma unroll
        for (int j = 0; j < 4; ++j) acc[i][j] = 0.f;

    for (int p = 0; p < 2; ++p) {
        __syncthreads();            // also covers xs-load on p==0
#pragma unroll
        for (int t = 0; t < 4; ++t) {
            const int idx = t * 256 + tid;
            const int kk = idx >> 4, c4 = idx & 15;
            *(float4*)&ws[kk][c4 * 4] =
                *(const float4*)(W + (size_t)(p * 64 + kk) * N_HID + c4 * 4);
        }
        __syncthreads();
#pragma unroll
        for (int k4 = 0; k4 < 16; ++k4) {
            float4 a[4], bb[4];
#pragma unroll
            for (int i = 0; i < 4; ++i)
                a[i] = *(const float4*)&xs[ty + 16 * i][p * 64 + k4 * 4];
#pragma unroll
            for (int j = 0; j < 4; ++j)
                bb[j] = *(const float4*)&ws[k4 * 4 + j][tx * 4];
#pragma unroll
            for (int i = 0; i < 4; ++i) {
                const float* ap = (const float*)&a[i];
#pragma unroll
                for (int j = 0; j < 4; ++j) {
                    const float* bp = (const float*)&bb[j];
#pragma unroll
                    for (int c = 0; c < 4; ++c)
                        acc[i][c] = fmaf(ap[j], bp[c], acc[i][c]);
                }
            }
        }
    }

    const float4 bias = *(const float4*)(b + tx * 4);
#pragma unroll
    for (int i = 0; i < 4; ++i) {
        const int node = n0 + ty + 16 * i;
        if (node < N_NODES) {
            float4 r;
            r.x = acc[i][0] + bias.x; r.y = acc[i][1] + bias.y;
            r.z = acc[i][2] + bias.z; r.w = acc[i][3] + bias.w;
            *(float4*)(h + (size_t)node * N_HID + tx * 4) = r;
        }
    }
}

// ---- MLP v2: both GEMMs fused per 64-node tile. z tile lives in LDS aliased
// over the input tile (dead after phase-1 k-loop). LDS 51 KB -> 3 blocks/CU.
__global__ __launch_bounds__(256) void mlp_kernel(
    const float* __restrict__ in, float* __restrict__ out,
    const float* __restrict__ W1, const float* __restrict__ b1,
    const float* __restrict__ W2, const float* __restrict__ b2)
{
    __shared__ float as[64][68];    // input tile, then z tile
    __shared__ float w1s[64][68];
    __shared__ float w2s[64][68];
    const int tid = threadIdx.x;
    const int tx = tid & 15, ty = tid >> 4;
    const int n0 = blockIdx.x * 64;

    // loads: in-tile + W1 + W2, 1024 float4 each
#pragma unroll
    for (int t = 0; t < 4; ++t) {
        const int idx = t * 256 + tid;
        const int m = idx >> 4, kv = idx & 15;
        float4 v = make_float4(0.f, 0.f, 0.f, 0.f);
        if (n0 + m < N_NODES)
            v = *(const float4*)(in + (size_t)(n0 + m) * N_HID + kv * 4);
        *(float4*)&as[m][kv * 4] = v;
        *(float4*)&w1s[m][kv * 4] = *(const float4*)(W1 + (size_t)m * N_HID + kv * 4);
        *(float4*)&w2s[m][kv * 4] = *(const float4*)(W2 + (size_t)m * N_HID + kv * 4);
    }
    __syncthreads();

    // phase 1: z = relu(in @ W1 + b1)
    float acc[4][4];
#pragma unroll
    for (int i = 0; i < 4; ++i)
#pragma unroll
        for (int j = 0; j < 4; ++j) acc[i][j] = 0.f;
#pragma unroll
    for (int k4 = 0; k4 < 16; ++k4) {
        float4 a[4], bb[4];
#pragma unroll
        for (int i = 0; i < 4; ++i)
            a[i] = *(const float4*)&as[ty + 16 * i][k4 * 4];
#pragma unroll
        for (int j = 0; j < 4; ++j)
            bb[j] = *(const float4*)&w1s[k4 * 4 + j][tx * 4];
#pragma unroll
        for (int i = 0; i < 4; ++i) {
            const float* ap = (const float*)&a[i];
#pragma unroll
            for (int j = 0; j < 4; ++j) {
                const float* bp = (const float*)&bb[j];
#pragma unroll
                for (int c = 0; c < 4; ++c)
                    acc[i][c] = fmaf(ap[j], bp[c], acc[i][c]);
            }
        }
    }
    const float4 bias1 = *(const float4*)(b1 + tx * 4);
    float4 z[4];
#pragma unroll
    for (int i = 0; i < 4; ++i) {
        z[i].x = fmaxf(acc[i][0] + bias1.x, 0.f);
        z[i].y = fmaxf(acc[i][1] + bias1.y, 0.f);
        z[i].z = fmaxf(acc[i][2] + bias1.z, 0.f);
        z[i].w = fmaxf(acc[i][3] + bias1.w, 0.f);
    }
    __syncthreads();               // all reads of as done
#pragma unroll
    for (int i = 0; i < 4; ++i)
        *(float4*)&as[ty + 16 * i][tx * 4] = z[i];
    __syncthreads();

    // phase 2: h = relu(z @ W2 + b2)
#pragma unroll
    for (int i = 0; i < 4; ++i)
#pragma unroll
        for (int j = 0; j < 4; ++j) acc[i][j] = 0.f;
#pragma unroll
    for (int k4 = 0; k4 < 16; ++k4) {
        float4 a[4], bb[4];
#pragma unroll
        for (int i = 0; i < 4; ++i)
            a[i] = *(const float4*)&as[ty + 16 * i][k4 * 4];
#pragma unroll
        for (int j = 0; j < 4; ++j)
            bb[j] = *(const float4*)&w2s[k4 * 4 + j][tx * 4];
#pragma unroll
        for (int i = 0; i < 4; ++i) {
            const float* ap = (const float*)&a[i];
#pragma unroll
            for (int j = 0; j < 4; ++j) {
                const float* bp = (const float*)&bb[j];
#pragma unroll
                for (int c = 0; c < 4; ++c)
                    acc[i][c] = fmaf(ap[j], bp[c], acc[i][c]);
            }
        }
    }
    const float4 bias2 = *(const float4*)(b2 + tx * 4);
#pragma unroll
    for (int i = 0; i < 4; ++i) {
        const int node = n0 + ty + 16 * i;
        if (node < N_NODES) {
            float4 r;
            r.x = fmaxf(acc[i][0] + bias2.x, 0.f);
            r.y = fmaxf(acc[i][1] + bias2.y, 0.f);
            r.z = fmaxf(acc[i][2] + bias2.z, 0.f);
            r.w = fmaxf(acc[i][3] + bias2.w, 0.f);
            *(float4*)(out + (size_t)node * N_HID + tx * 4) = r;
        }
    }
}

// ---------------- pool: g[graph] = sum_{batch[i]==graph} h[i] ----------------
__global__ __launch_bounds__(256) void pool_kernel(
    const float* __restrict__ h, const int* __restrict__ batch,
    float* __restrict__ g)
{
    const int graph = blockIdx.x;
    int l = 0, r = N_NODES;
    while (l < r) { int m = (l + r) >> 1; if (batch[m] < graph) l = m + 1; else r = m; }
    const int lo = l;
    r = N_NODES;
    while (l < r) { int m = (l + r) >> 1; if (batch[m] < graph + 1) l = m + 1; else r = m; }
    const int hi = l;

    const int lane = threadIdx.x & 63;
    const int wave = threadIdx.x >> 6;
    float acc = 0.0f;
    for (int i = lo + wave; i < hi; i += 4)
        acc += h[(size_t)i * N_HID + lane];
    __shared__ float sacc[4][N_HID];
    sacc[wave][lane] = acc;
    __syncthreads();
    if (wave == 0) {
        g[(size_t)graph * N_HID + lane] =
            sacc[0][lane] + sacc[1][lane] + sacc[2][lane] + sacc[3][lane];
    }
}

// ---------------- head: relu(g@post_w+post_b) @ ro_w + ro_b -> log_softmax ----
__global__ __launch_bounds__(256) void head_kernel(
    const float* __restrict__ g,
    const float* __restrict__ Wp, const float* __restrict__ bp,
    const float* __restrict__ Wr, const float* __restrict__ br,
    float* __restrict__ out)
{
    const int lane = threadIdx.x & 63;
    const int wave = threadIdx.x >> 6;
    const int graph = blockIdx.x * 4 + wave;

    float wp[N_HID];
#pragma unroll
    for (int k = 0; k < N_HID; ++k) wp[k] = Wp[k * N_HID + lane];

    const int un = __builtin_amdgcn_readfirstlane(graph);
    const float* row = g + (size_t)un * N_HID;
    float acc = bp[lane];
#pragma unroll
    for (int k = 0; k < N_HID; ++k) acc = fmaf(row[k], wp[k], acc);
    const float z = fmaxf(acc, 0.0f);

    float logit = (lane < N_CLASS) ? br[lane] : 0.0f;
#pragma unroll
    for (int k = 0; k < N_HID; ++k) {
        const float zk = __int_as_float(
            __builtin_amdgcn_readlane(__float_as_int(z), k));  // exec-ignoring
        if (lane < N_CLASS)
            logit = fmaf(zk, Wr[k * N_CLASS + lane], logit);
    }

    __shared__ float slog[4][N_CLASS];
    if (lane < N_CLASS) slog[wave][lane] = logit;
    if (lane < N_CLASS) {
        float m = -INFINITY;
#pragma unroll
        for (int c = 0; c < N_CLASS; ++c) m = fmaxf(m, slog[wave][c]);
        float sum = 0.0f;
#pragma unroll
        for (int c = 0; c < N_CLASS; ++c) sum += expf(slog[wave][c] - m);
        out[(size_t)un * N_CLASS + lane] = logit - m - logf(sum);
    }
}

extern "C" void kernel_launch(void* const* d_in, const int* in_sizes, int n_in,
                              void* d_out, int out_size, void* d_ws, size_t ws_size,
                              hipStream_t stream)
{
    const float* x       = (const float*)d_in[0];
    const int*   ei      = (const int*)d_in[1];   // [2, E]: row0=src, row1=dst
    const int*   batch   = (const int*)d_in[2];
    const float* pre_w   = (const float*)d_in[3];
    const float* pre_b   = (const float*)d_in[4];
    const float* conv_w1 = (const float*)d_in[5];
    const float* conv_b1 = (const float*)d_in[6];
    const float* conv_w2 = (const float*)d_in[7];
    const float* conv_b2 = (const float*)d_in[8];
    const float* post_w  = (const float*)d_in[9];
    const float* post_b  = (const float*)d_in[10];
    const float* ro_w    = (const float*)d_in[11];
    const float* ro_b    = (const float*)d_in[12];
    float* out = (float*)d_out;

    // workspace layout (~59 MB)
    float* h      = (float*)d_ws;                          // 6.4M f
    float* agg    = h + (size_t)N_NODES * N_HID;           // 6.4M f
    float* g      = agg + (size_t)N_NODES * N_HID;         // 64K f
    int*   deg    = (int*)(g + (size_t)N_GRAPHS * N_HID);  // 100K i
    int*   row    = deg + N_NODES;                         // 100K i
    int*   pre    = row + N_NODES;                         // 100K i (scan temp)
    int*   bsum   = pre + N_NODES;                         // 128 i
    int*   csr    = bsum + 128;                            // 1.6M i
    int*   rank   = (int*)agg;   // alias: rank dead before gather writes agg

    // ---- CSR build (once; reused by all 3 layers) ----
    zero_kernel<<<128, 256, 0, stream>>>(deg, N_NODES);
    hist_kernel<<<2048, 256, 0, stream>>>(ei, deg, rank);
    scan1_kernel<<<SCAN_NB, 256, 0, stream>>>(deg, pre, bsum);
    scan2_kernel<<<1, 64, 0, stream>>>(bsum);
    scan3_kernel<<<128, 256, 0, stream>>>(pre, bsum, row);
    fill_kernel<<<2048, 256, 0, stream>>>(ei, rank, row, csr);

    // ---- network ----
    pre_kernel<<<NTILES, 256, 0, stream>>>(x, pre_w, pre_b, h);

    for (int l = 0; l < 3; ++l) {
        gather_kernel<<<6144, 256, 0, stream>>>(h, agg, csr, row, deg);
        mlp_kernel<<<NTILES, 256, 0, stream>>>(
            agg, h,
            conv_w1 + (size_t)l * N_HID * N_HID, conv_b1 + (size_t)l * N_HID,
            conv_w2 + (size_t)l * N_HID * N_HID, conv_b2 + (size_t)l * N_HID);
    }

    pool_kernel<<<N_GRAPHS, 256, 0, stream>>>(h, batch, g);
    head_kernel<<<N_GRAPHS / 4, 256, 0, stream>>>(g, post_w, post_b, ro_w, ro_b, out);
}

// Round 6
// 527.799 us; speedup vs baseline: 1.2715x; 1.2715x over previous
//
#include <hip/hip_runtime.h>
#include <math.h>

#define N_NODES  100000
#define N_FEAT   128
#define N_HID    64
#define N_CLASS  10
#define N_GRAPHS 1000
#define N_EDGES  1600000
#define SCAN_NB  98        // ceil(100000/1024)
#define NPASS    6
#define PRANGE   16667     // ceil(100000/6)
#define NTILES   1563      // ceil(100000/64)

// ---------------- zero int array ----------------
__global__ __launch_bounds__(256) void zero_kernel(int* __restrict__ p, int n)
{
    int stride = gridDim.x * blockDim.x;
    for (int i = blockIdx.x * blockDim.x + threadIdx.x; i < n; i += stride)
        p[i] = 0;
}

// ---- degree histogram over dst; atomic return value IS the edge's rank ----
__global__ __launch_bounds__(256) void hist_kernel(
    const int* __restrict__ ei, int* __restrict__ deg, int* __restrict__ rank)
{
    int stride = gridDim.x * blockDim.x;
    for (int e = blockIdx.x * blockDim.x + threadIdx.x; e < N_EDGES; e += stride)
        rank[e] = atomicAdd(&deg[ei[N_EDGES + e]], 1);
}

// ---------------- scan stage 1: per-block (1024 elems) exclusive scan ----------
__global__ __launch_bounds__(256) void scan1_kernel(
    const int* __restrict__ deg, int* __restrict__ pre, int* __restrict__ bsum)
{
    __shared__ int tsum[256];
    const int base = blockIdx.x * 1024 + threadIdx.x * 4;
    int v[4];
#pragma unroll
    for (int j = 0; j < 4; ++j)
        v[j] = (base + j < N_NODES) ? deg[base + j] : 0;
    int run = 0;
#pragma unroll
    for (int j = 0; j < 4; ++j) { int t = v[j]; v[j] = run; run += t; }
    tsum[threadIdx.x] = run;
    __syncthreads();
    for (int off = 1; off < 256; off <<= 1) {
        int t = (threadIdx.x >= off) ? tsum[threadIdx.x - off] : 0;
        __syncthreads();
        tsum[threadIdx.x] += t;
        __syncthreads();
    }
    const int excl = (threadIdx.x > 0) ? tsum[threadIdx.x - 1] : 0;
#pragma unroll
    for (int j = 0; j < 4; ++j)
        if (base + j < N_NODES) pre[base + j] = v[j] + excl;
    if (threadIdx.x == 255) bsum[blockIdx.x] = tsum[255];
}

// ---------------- scan stage 2: serial scan of 98 block sums ----------------
__global__ void scan2_kernel(int* __restrict__ bsum)
{
    if (threadIdx.x == 0 && blockIdx.x == 0) {
        int run = 0;
        for (int i = 0; i < SCAN_NB; ++i) { int t = bsum[i]; bsum[i] = run; run += t; }
    }
}

// ---------------- scan stage 3: add block offset -> row ptr ----------------
__global__ __launch_bounds__(256) void scan3_kernel(
    const int* __restrict__ pre, const int* __restrict__ bsum,
    int* __restrict__ row)
{
    int stride = gridDim.x * blockDim.x;
    for (int i = blockIdx.x * blockDim.x + threadIdx.x; i < N_NODES; i += stride)
        row[i] = pre[i] + bsum[i >> 10];
}

// ---- CSR fill: no atomics (pos = row[d]+rank[e]); 6 dst-range passes so the
// ---- active csr/row window (~1.1 MB / 67 KB) stays L2-resident ----
__global__ __launch_bounds__(256) void fill_kernel(
    const int* __restrict__ ei, const int* __restrict__ rank,
    const int* __restrict__ row, int* __restrict__ csr)
{
    const int stride = gridDim.x * blockDim.x;
    const int tid0 = blockIdx.x * blockDim.x + threadIdx.x;
    for (int pass = 0; pass < NPASS; ++pass) {
        const int lo = pass * PRANGE;
        const int hi = lo + PRANGE;
        for (int e = tid0; e < N_EDGES; e += stride) {
            const int d = ei[N_EDGES + e];
            if (d >= lo && d < hi)
                csr[row[d] + rank[e]] = ei[e];
        }
    }
}

// ---- gather: agg[i] = h[i] + sum_{e in row[i]} h[csr[e]] ----
// one wave per node; uniform trip count so every __shfl source lane is active
// (ds_bpermute from an inactive lane is undefined — round-3 bug).
__global__ __launch_bounds__(256) void gather_kernel(
    const float* __restrict__ h, float* __restrict__ agg,
    const int* __restrict__ csr, const int* __restrict__ row,
    const int* __restrict__ deg)
{
    const int lane = threadIdx.x & 63;
    const int grp  = lane >> 4;       // 0..3
    const int sub  = lane & 15;       // 0..15
    const int nw = gridDim.x * 4;
    for (int node = blockIdx.x * 4 + (threadIdx.x >> 6); node < N_NODES; node += nw) {
        const int un = __builtin_amdgcn_readfirstlane(node);
        const int lo = __builtin_amdgcn_readfirstlane(row[un]);
        const int n  = __builtin_amdgcn_readfirstlane(deg[un]);
        int eidx = 0;
        if (lane < n) eidx = csr[lo + lane];    // whole bucket, one load
        float ax = 0.f, ay = 0.f, az = 0.f, aw = 0.f;
        if (grp == 0) {
            const float4 a = *(const float4*)(h + (size_t)un * N_HID + (sub << 2));
            ax += a.x; ay += a.y; az += a.z; aw += a.w;
        }
        for (int eb = 0; eb < n; eb += 8) {     // UNIFORM trip count
            const int j0 = eb + grp;
            const int j1 = j0 + 4;
            const int s0 = __shfl(eidx, j0, 64);
            const int s1 = __shfl(eidx, j1, 64);
            if (j0 < n) {
                const float4 a = *(const float4*)(h + (size_t)s0 * N_HID + (sub << 2));
                ax += a.x; ay += a.y; az += a.z; aw += a.w;
            }
            if (j1 < n) {
                const float4 a = *(const float4*)(h + (size_t)s1 * N_HID + (sub << 2));
                ax += a.x; ay += a.y; az += a.z; aw += a.w;
            }
        }
        ax += __shfl_xor(ax, 16, 64); ay += __shfl_xor(ay, 16, 64);
        az += __shfl_xor(az, 16, 64); aw += __shfl_xor(aw, 16, 64);
        ax += __shfl_xor(ax, 32, 64); ay += __shfl_xor(ay, 32, 64);
        az += __shfl_xor(az, 32, 64); aw += __shfl_xor(aw, 32, 64);
        if (grp == 0) {
            float4 r = make_float4(ax, ay, az, aw);
            *(float4*)(agg + (size_t)un * N_HID + (sub << 2)) = r;
        }
    }
}

// ---- pre v3: LDS-tiled GEMM, K split in two 64-halves so BOTH x-tile and
// W-tile fit in 2x17.4KB = 34.8KB LDS -> 4 blocks/CU. __launch_bounds__(256,4)
// caps VGPR at 128; unroll-2 keeps genuine pressure ~110 (round-5 full unroll
// hit 256 VGPR -> 9% occupancy -> 80us).
__global__ __launch_bounds__(256, 4) void pre_kernel(
    const float* __restrict__ x, const float* __restrict__ W,
    const float* __restrict__ b, float* __restrict__ h)
{
    __shared__ float xs[64][68];    // x half-tile [m][kk]
    __shared__ float ws[64][68];    // W half     [kk][c]
    const int tid = threadIdx.x;
    const int tx = tid & 15, ty = tid >> 4;
    const int n0 = blockIdx.x * 64;

    float acc[4][4];
#pragma unroll
    for (int i = 0; i < 4; ++i)
#pragma unroll
        for (int j = 0; j < 4; ++j) acc[i][j] = 0.f;

    for (int p = 0; p < 2; ++p) {
        __syncthreads();            // prev phase reads done
#pragma unroll
        for (int t = 0; t < 4; ++t) {
            const int idx = t * 256 + tid;
            const int m = idx >> 4, kv = idx & 15;
            float4 v = make_float4(0.f, 0.f, 0.f, 0.f);
            if (n0 + m < N_NODES)
                v = *(const float4*)(x + (size_t)(n0 + m) * N_FEAT + p * 64 + kv * 4);
            *(float4*)&xs[m][kv * 4] = v;
            *(float4*)&ws[m][kv * 4] =
                *(const float4*)(W + (size_t)(p * 64 + m) * N_HID + kv * 4);
        }
        __syncthreads();
#pragma unroll 2
        for (int k4 = 0; k4 < 16; ++k4) {
            float4 a[4], bb[4];
#pragma unroll
            for (int i = 0; i < 4; ++i)
                a[i] = *(const float4*)&xs[ty + 16 * i][k4 * 4];
#pragma unroll
            for (int j = 0; j < 4; ++j)
                bb[j] = *(const float4*)&ws[k4 * 4 + j][tx * 4];
#pragma unroll
            for (int i = 0; i < 4; ++i) {
                const float* ap = (const float*)&a[i];
#pragma unroll
                for (int j = 0; j < 4; ++j) {
                    const float* bp = (const float*)&bb[j];
#pragma unroll
                    for (int c = 0; c < 4; ++c)
                        acc[i][c] = fmaf(ap[j], bp[c], acc[i][c]);
                }
            }
        }
    }

    const float4 bias = *(const float4*)(b + tx * 4);
#pragma unroll
    for (int i = 0; i < 4; ++i) {
        const int node = n0 + ty + 16 * i;
        if (node < N_NODES) {
            float4 r;
            r.x = acc[i][0] + bias.x; r.y = acc[i][1] + bias.y;
            r.z = acc[i][2] + bias.z; r.w = acc[i][3] + bias.w;
            *(float4*)(h + (size_t)node * N_HID + tx * 4) = r;
        }
    }
}

// ---- MLP v3: fused 2-GEMM per 64-node tile; ONE weight buffer reloaded
// W1 -> W2 between phases (W2 re-fetch is L2-served). LDS 34.8KB -> 4
// blocks/CU; launch_bounds(256,4) caps 128 VGPR; unroll-2 avoids spill.
__global__ __launch_bounds__(256, 4) void mlp_kernel(
    const float* __restrict__ in, float* __restrict__ out,
    const float* __restrict__ W1, const float* __restrict__ b1,
    const float* __restrict__ W2, const float* __restrict__ b2)
{
    __shared__ float as[64][68];    // input tile, then z tile
    __shared__ float ws[64][68];    // W1, then W2
    const int tid = threadIdx.x;
    const int tx = tid & 15, ty = tid >> 4;
    const int n0 = blockIdx.x * 64;

#pragma unroll
    for (int t = 0; t < 4; ++t) {
        const int idx = t * 256 + tid;
        const int m = idx >> 4, kv = idx & 15;
        float4 v = make_float4(0.f, 0.f, 0.f, 0.f);
        if (n0 + m < N_NODES)
            v = *(const float4*)(in + (size_t)(n0 + m) * N_HID + kv * 4);
        *(float4*)&as[m][kv * 4] = v;
        *(float4*)&ws[m][kv * 4] = *(const float4*)(W1 + (size_t)m * N_HID + kv * 4);
    }
    __syncthreads();

    // phase 1: z = relu(in @ W1 + b1)
    float acc[4][4];
#pragma unroll
    for (int i = 0; i < 4; ++i)
#pragma unroll
        for (int j = 0; j < 4; ++j) acc[i][j] = 0.f;
#pragma unroll 2
    for (int k4 = 0; k4 < 16; ++k4) {
        float4 a[4], bb[4];
#pragma unroll
        for (int i = 0; i < 4; ++i)
            a[i] = *(const float4*)&as[ty + 16 * i][k4 * 4];
#pragma unroll
        for (int j = 0; j < 4; ++j)
            bb[j] = *(const float4*)&ws[k4 * 4 + j][tx * 4];
#pragma unroll
        for (int i = 0; i < 4; ++i) {
            const float* ap = (const float*)&a[i];
#pragma unroll
            for (int j = 0; j < 4; ++j) {
                const float* bp = (const float*)&bb[j];
#pragma unroll
                for (int c = 0; c < 4; ++c)
                    acc[i][c] = fmaf(ap[j], bp[c], acc[i][c]);
            }
        }
    }
    const float4 bias1 = *(const float4*)(b1 + tx * 4);
    float4 z[4];
#pragma unroll
    for (int i = 0; i < 4; ++i) {
        z[i].x = fmaxf(acc[i][0] + bias1.x, 0.f);
        z[i].y = fmaxf(acc[i][1] + bias1.y, 0.f);
        z[i].z = fmaxf(acc[i][2] + bias1.z, 0.f);
        z[i].w = fmaxf(acc[i][3] + bias1.w, 0.f);
    }
    __syncthreads();               // all phase-1 reads of as/ws done
#pragma unroll
    for (int i = 0; i < 4; ++i)
        *(float4*)&as[ty + 16 * i][tx * 4] = z[i];
#pragma unroll
    for (int t = 0; t < 4; ++t) {
        const int idx = t * 256 + tid;
        const int m = idx >> 4, kv = idx & 15;
        *(float4*)&ws[m][kv * 4] = *(const float4*)(W2 + (size_t)m * N_HID + kv * 4);
    }
    __syncthreads();

    // phase 2: h = relu(z @ W2 + b2)
#pragma unroll
    for (int i = 0; i < 4; ++i)
#pragma unroll
        for (int j = 0; j < 4; ++j) acc[i][j] = 0.f;
#pragma unroll 2
    for (int k4 = 0; k4 < 16; ++k4) {
        float4 a[4], bb[4];
#pragma unroll
        for (int i = 0; i < 4; ++i)
            a[i] = *(const float4*)&as[ty + 16 * i][k4 * 4];
#pragma unroll
        for (int j = 0; j < 4; ++j)
            bb[j] = *(const float4*)&ws[k4 * 4 + j][tx * 4];
#pragma unroll
        for (int i = 0; i < 4; ++i) {
            const float* ap = (const float*)&a[i];
#pragma unroll
            for (int j = 0; j < 4; ++j) {
                const float* bp = (const float*)&bb[j];
#pragma unroll
                for (int c = 0; c < 4; ++c)
                    acc[i][c] = fmaf(ap[j], bp[c], acc[i][c]);
            }
        }
    }
    const float4 bias2 = *(const float4*)(b2 + tx * 4);
#pragma unroll
    for (int i = 0; i < 4; ++i) {
        const int node = n0 + ty + 16 * i;
        if (node < N_NODES) {
            float4 r;
            r.x = fmaxf(acc[i][0] + bias2.x, 0.f);
            r.y = fmaxf(acc[i][1] + bias2.y, 0.f);
            r.z = fmaxf(acc[i][2] + bias2.z, 0.f);
            r.w = fmaxf(acc[i][3] + bias2.w, 0.f);
            *(float4*)(out + (size_t)node * N_HID + tx * 4) = r;
        }
    }
}

// ---------------- pool: g[graph] = sum_{batch[i]==graph} h[i] ----------------
__global__ __launch_bounds__(256) void pool_kernel(
    const float* __restrict__ h, const int* __restrict__ batch,
    float* __restrict__ g)
{
    const int graph = blockIdx.x;
    int l = 0, r = N_NODES;
    while (l < r) { int m = (l + r) >> 1; if (batch[m] < graph) l = m + 1; else r = m; }
    const int lo = l;
    r = N_NODES;
    while (l < r) { int m = (l + r) >> 1; if (batch[m] < graph + 1) l = m + 1; else r = m; }
    const int hi = l;

    const int lane = threadIdx.x & 63;
    const int wave = threadIdx.x >> 6;
    float acc = 0.0f;
    for (int i = lo + wave; i < hi; i += 4)
        acc += h[(size_t)i * N_HID + lane];
    __shared__ float sacc[4][N_HID];
    sacc[wave][lane] = acc;
    __syncthreads();
    if (wave == 0) {
        g[(size_t)graph * N_HID + lane] =
            sacc[0][lane] + sacc[1][lane] + sacc[2][lane] + sacc[3][lane];
    }
}

// ---------------- head: relu(g@post_w+post_b) @ ro_w + ro_b -> log_softmax ----
__global__ __launch_bounds__(256) void head_kernel(
    const float* __restrict__ g,
    const float* __restrict__ Wp, const float* __restrict__ bp,
    const float* __restrict__ Wr, const float* __restrict__ br,
    float* __restrict__ out)
{
    const int lane = threadIdx.x & 63;
    const int wave = threadIdx.x >> 6;
    const int graph = blockIdx.x * 4 + wave;

    float wp[N_HID];
#pragma unroll
    for (int k = 0; k < N_HID; ++k) wp[k] = Wp[k * N_HID + lane];

    const int un = __builtin_amdgcn_readfirstlane(graph);
    const float* row = g + (size_t)un * N_HID;
    float acc = bp[lane];
#pragma unroll
    for (int k = 0; k < N_HID; ++k) acc = fmaf(row[k], wp[k], acc);
    const float z = fmaxf(acc, 0.0f);

    float logit = (lane < N_CLASS) ? br[lane] : 0.0f;
#pragma unroll
    for (int k = 0; k < N_HID; ++k) {
        const float zk = __int_as_float(
            __builtin_amdgcn_readlane(__float_as_int(z), k));  // exec-ignoring
        if (lane < N_CLASS)
            logit = fmaf(zk, Wr[k * N_CLASS + lane], logit);
    }

    __shared__ float slog[4][N_CLASS];
    if (lane < N_CLASS) slog[wave][lane] = logit;
    if (lane < N_CLASS) {
        float m = -INFINITY;
#pragma unroll
        for (int c = 0; c < N_CLASS; ++c) m = fmaxf(m, slog[wave][c]);
        float sum = 0.0f;
#pragma unroll
        for (int c = 0; c < N_CLASS; ++c) sum += expf(slog[wave][c] - m);
        out[(size_t)un * N_CLASS + lane] = logit - m - logf(sum);
    }
}

extern "C" void kernel_launch(void* const* d_in, const int* in_sizes, int n_in,
                              void* d_out, int out_size, void* d_ws, size_t ws_size,
                              hipStream_t stream)
{
    const float* x       = (const float*)d_in[0];
    const int*   ei      = (const int*)d_in[1];   // [2, E]: row0=src, row1=dst
    const int*   batch   = (const int*)d_in[2];
    const float* pre_w   = (const float*)d_in[3];
    const float* pre_b   = (const float*)d_in[4];
    const float* conv_w1 = (const float*)d_in[5];
    const float* conv_b1 = (const float*)d_in[6];
    const float* conv_w2 = (const float*)d_in[7];
    const float* conv_b2 = (const float*)d_in[8];
    const float* post_w  = (const float*)d_in[9];
    const float* post_b  = (const float*)d_in[10];
    const float* ro_w    = (const float*)d_in[11];
    const float* ro_b    = (const float*)d_in[12];
    float* out = (float*)d_out;

    // workspace layout (~59 MB)
    float* h      = (float*)d_ws;                          // 6.4M f
    float* agg    = h + (size_t)N_NODES * N_HID;           // 6.4M f
    float* g      = agg + (size_t)N_NODES * N_HID;         // 64K f
    int*   deg    = (int*)(g + (size_t)N_GRAPHS * N_HID);  // 100K i
    int*   row    = deg + N_NODES;                         // 100K i
    int*   pre    = row + N_NODES;                         // 100K i (scan temp)
    int*   bsum   = pre + N_NODES;                         // 128 i
    int*   csr    = bsum + 128;                            // 1.6M i
    int*   rank   = (int*)agg;   // alias: rank dead before gather writes agg

    // ---- CSR build (once; reused by all 3 layers) ----
    zero_kernel<<<128, 256, 0, stream>>>(deg, N_NODES);
    hist_kernel<<<2048, 256, 0, stream>>>(ei, deg, rank);
    scan1_kernel<<<SCAN_NB, 256, 0, stream>>>(deg, pre, bsum);
    scan2_kernel<<<1, 64, 0, stream>>>(bsum);
    scan3_kernel<<<128, 256, 0, stream>>>(pre, bsum, row);
    fill_kernel<<<2048, 256, 0, stream>>>(ei, rank, row, csr);

    // ---- network ----
    pre_kernel<<<NTILES, 256, 0, stream>>>(x, pre_w, pre_b, h);

    for (int l = 0; l < 3; ++l) {
        gather_kernel<<<6144, 256, 0, stream>>>(h, agg, csr, row, deg);
        mlp_kernel<<<NTILES, 256, 0, stream>>>(
            agg, h,
            conv_w1 + (size_t)l * N_HID * N_HID, conv_b1 + (size_t)l * N_HID,
            conv_w2 + (size_t)l * N_HID * N_HID, conv_b2 + (size_t)l * N_HID);
    }

    pool_kernel<<<N_GRAPHS, 256, 0, stream>>>(h, batch, g);
    head_kernel<<<N_GRAPHS / 4, 256, 0, stream>>>(g, post_w, post_b, ro_w, ro_b, out);
}